// Round 2
// baseline (813.469 us; speedup 1.0000x reference)
//
#include <hip/hip_runtime.h>
#include <hip/hip_cooperative_groups.h>

namespace cg = cooperative_groups;

#define B 8
#define H 4096
#define NH 32
#define HD 128
#define P 2047
#define T 2048          // P + 1 (cache + appended token)
#define HQKV 12288      // 3*H

// One cooperative kernel, 256 blocks x 1024 threads (1 block/CU, 16 waves).
// Stage 0: zero qkv ws + d_out (atomic k-split targets).
// Stage 1: qkv = x@Wqkv + bqkv   (6 waves/block active, 32-way k-split, atomics)
// Stage 2: attention, one block per (b,h), float4 loads, 2 t per wave-iter.
// Stage 3: out = attn@Wproj + bproj (4 waves/block active, 64-way k-split).
__global__ __launch_bounds__(1024, 4) void fused_attn_kernel(
    const float* __restrict__ x,
    const float* __restrict__ cache_k,
    const float* __restrict__ cache_v,
    const float* __restrict__ Wqkv,
    const float* __restrict__ bqkv,
    const float* __restrict__ Wproj,
    const float* __restrict__ bproj,
    float* __restrict__ qkv,        // ws: B*HQKV
    float* __restrict__ attn_out,   // ws: B*H
    float* __restrict__ out)        // d_out: B*H
{
    cg::grid_group grid = cg::this_grid();

    const int tid  = threadIdx.x;
    const int wave = tid >> 6;
    const int lane = tid & 63;

    // ---------------- stage 0: zero the atomic targets ----------------
    {
        int g = blockIdx.x * 1024 + tid;          // [0, 262144)
        float4 z = make_float4(0.f, 0.f, 0.f, 0.f);
        if (g < 24576) {                          // qkv: 98304 floats
            ((float4*)qkv)[g] = z;
        } else if (g < 32768) {                   // out: 32768 floats
            ((float4*)out)[g - 24576] = z;
        }
    }
    grid.sync();

    // ---------------- stage 1: qkv GEMM (x[8,4096] @ Wqkv[4096,12288]) ----
    // 1536 active waves: 48 col-groups (256 cols each) x 32 k-chunks (128 rows).
    if (wave < 6) {
        const int id  = blockIdx.x * 6 + wave;    // [0, 1536)
        const int kc  = id / 48;                  // [0, 32)
        const int cgq = id % 48;                  // [0, 48)
        const int col = cgq * 256 + lane * 4;
        const int k0  = kc * 128;

        float4 acc[B];
#pragma unroll
        for (int b = 0; b < B; ++b) acc[b] = make_float4(0.f, 0.f, 0.f, 0.f);

        const float* wp = Wqkv + (size_t)k0 * HQKV + col;
        const float* xp = x + k0;

        for (int k = 0; k < 128; k += 4) {
            float4 w0 = *(const float4*)(wp + (size_t)(k + 0) * HQKV);
            float4 w1 = *(const float4*)(wp + (size_t)(k + 1) * HQKV);
            float4 w2 = *(const float4*)(wp + (size_t)(k + 2) * HQKV);
            float4 w3 = *(const float4*)(wp + (size_t)(k + 3) * HQKV);
#pragma unroll
            for (int b = 0; b < B; ++b) {
                float4 xv = *(const float4*)(xp + b * H + k);  // wave-uniform
                acc[b].x += xv.x * w0.x + xv.y * w1.x + xv.z * w2.x + xv.w * w3.x;
                acc[b].y += xv.x * w0.y + xv.y * w1.y + xv.z * w2.y + xv.w * w3.y;
                acc[b].z += xv.x * w0.z + xv.y * w1.z + xv.z * w2.z + xv.w * w3.z;
                acc[b].w += xv.x * w0.w + xv.y * w1.w + xv.z * w2.w + xv.w * w3.w;
            }
        }
        if (kc == 0) {                            // fold bias once per column
            float4 bias = *(const float4*)(bqkv + col);
#pragma unroll
            for (int b = 0; b < B; ++b) {
                acc[b].x += bias.x; acc[b].y += bias.y;
                acc[b].z += bias.z; acc[b].w += bias.w;
            }
        }
#pragma unroll
        for (int b = 0; b < B; ++b) {
            float* q = qkv + b * HQKV + col;
            atomicAdd(q + 0, acc[b].x);
            atomicAdd(q + 1, acc[b].y);
            atomicAdd(q + 2, acc[b].z);
            atomicAdd(q + 3, acc[b].w);
        }
    }
    grid.sync();

    // ---------------- stage 2: attention, block = (b,h) ----------------
    __shared__ float sc[T];              // 8 KB scores -> probabilities
    __shared__ float wred[16];
    __shared__ float ored[16][HD];       // 8 KB cross-wave O reduction
    __shared__ float s_stats[2];

    {
        const int b    = blockIdx.x >> 5;
        const int h    = blockIdx.x & 31;
        const int sl   = lane & 31;          // sub-lane within half-wave
        const int half = lane >> 5;          // 0 -> even t, 1 -> odd t
        const float scale = 0.08838834764831845f;  // 1/sqrt(128)
        const size_t tstride = (size_t)B * NH * HD;

        const float* qp = qkv + b * HQKV + h * HD;
        float4 q4 = *(const float4*)(qp + 4 * sl);

        const float* kbase = cache_k + ((size_t)b * NH + h) * HD + 4 * sl;
        const float* knew  = qkv + b * HQKV + H + h * HD + 4 * sl;

        // ---- phase 1: scores (2 t per wave-iteration, 1KB/wave loads) ----
#pragma unroll 4
        for (int pr = wave; pr < T / 2; pr += 16) {
            int t = 2 * pr + half;
            const float* kp = (t < P) ? (kbase + (size_t)t * tstride) : knew;
            float4 k4 = *(const float4*)kp;
            float ps = q4.x * k4.x + q4.y * k4.y + q4.z * k4.z + q4.w * k4.w;
#pragma unroll
            for (int off = 16; off >= 1; off >>= 1) ps += __shfl_xor(ps, off);
            if (sl == 0) sc[t] = ps * scale;
        }
        __syncthreads();

        // ---- softmax stats ----
        float m = fmaxf(sc[tid], sc[tid + 1024]);
#pragma unroll
        for (int off = 32; off >= 1; off >>= 1) m = fmaxf(m, __shfl_xor(m, off));
        if (lane == 0) wred[wave] = m;
        __syncthreads();
        if (tid == 0) {
            float mm = wred[0];
#pragma unroll
            for (int w = 1; w < 16; ++w) mm = fmaxf(mm, wred[w]);
            s_stats[0] = mm;
        }
        __syncthreads();
        const float gm = s_stats[0];
        float p0 = __expf(sc[tid] - gm);
        float p1 = __expf(sc[tid + 1024] - gm);
        sc[tid] = p0;
        sc[tid + 1024] = p1;
        float ls = p0 + p1;
#pragma unroll
        for (int off = 32; off >= 1; off >>= 1) ls += __shfl_xor(ls, off);
        if (lane == 0) wred[wave] = ls;
        __syncthreads();
        if (tid == 0) {
            float ss = 0.f;
#pragma unroll
            for (int w = 0; w < 16; ++w) ss += wred[w];
            s_stats[1] = ss;
        }
        __syncthreads();
        const float inv_l = 1.0f / s_stats[1];

        // ---- phase 2: O = sum_t p_t * v_t ----
        const float* vbase = cache_v + ((size_t)b * NH + h) * HD + 4 * sl;
        const float* vnew  = qkv + b * HQKV + 2 * H + h * HD + 4 * sl;
        float4 o4 = make_float4(0.f, 0.f, 0.f, 0.f);
#pragma unroll 4
        for (int pr = wave; pr < T / 2; pr += 16) {
            int t = 2 * pr + half;
            const float* vp = (t < P) ? (vbase + (size_t)t * tstride) : vnew;
            float4 v4 = *(const float4*)vp;
            float p = sc[t];
            o4.x += p * v4.x; o4.y += p * v4.y;
            o4.z += p * v4.z; o4.w += p * v4.w;
        }
        // combine even-t half with odd-t half
        o4.x += __shfl_xor(o4.x, 32);
        o4.y += __shfl_xor(o4.y, 32);
        o4.z += __shfl_xor(o4.z, 32);
        o4.w += __shfl_xor(o4.w, 32);
        if (half == 0) *(float4*)&ored[wave][4 * sl] = o4;
        __syncthreads();
        if (tid < HD) {
            float s = 0.f;
#pragma unroll
            for (int w = 0; w < 16; ++w) s += ored[w][tid];
            attn_out[b * H + h * HD + tid] = s * inv_l;
        }
    }
    grid.sync();

    // ---------------- stage 3: out = attn_out @ Wproj + bproj ----------
    // 1024 active waves: 16 col-groups (256 cols) x 64 k-chunks (64 rows).
    if (wave < 4) {
        const int id  = blockIdx.x * 4 + wave;    // [0, 1024)
        const int kc  = id >> 4;                  // [0, 64)
        const int cgp = id & 15;                  // [0, 16)
        const int col = cgp * 256 + lane * 4;
        const int k0  = kc * 64;

        float4 acc[B];
#pragma unroll
        for (int b = 0; b < B; ++b) acc[b] = make_float4(0.f, 0.f, 0.f, 0.f);

        const float* wp = Wproj + (size_t)k0 * H + col;
        const float* xp = attn_out + k0;

        for (int k = 0; k < 64; k += 4) {
            float4 w0 = *(const float4*)(wp + (size_t)(k + 0) * H);
            float4 w1 = *(const float4*)(wp + (size_t)(k + 1) * H);
            float4 w2 = *(const float4*)(wp + (size_t)(k + 2) * H);
            float4 w3 = *(const float4*)(wp + (size_t)(k + 3) * H);
#pragma unroll
            for (int b = 0; b < B; ++b) {
                float4 xv = *(const float4*)(xp + b * H + k);  // wave-uniform
                acc[b].x += xv.x * w0.x + xv.y * w1.x + xv.z * w2.x + xv.w * w3.x;
                acc[b].y += xv.x * w0.y + xv.y * w1.y + xv.z * w2.y + xv.w * w3.y;
                acc[b].z += xv.x * w0.z + xv.y * w1.z + xv.z * w2.z + xv.w * w3.z;
                acc[b].w += xv.x * w0.w + xv.y * w1.w + xv.z * w2.w + xv.w * w3.w;
            }
        }
        if (kc == 0) {
            float4 bias = *(const float4*)(bproj + col);
#pragma unroll
            for (int b = 0; b < B; ++b) {
                acc[b].x += bias.x; acc[b].y += bias.y;
                acc[b].z += bias.z; acc[b].w += bias.w;
            }
        }
#pragma unroll
        for (int b = 0; b < B; ++b) {
            float* o = out + b * H + col;
            atomicAdd(o + 0, acc[b].x);
            atomicAdd(o + 1, acc[b].y);
            atomicAdd(o + 2, acc[b].z);
            atomicAdd(o + 3, acc[b].w);
        }
    }
}

// ---------------------------------------------------------------------------
extern "C" void kernel_launch(void* const* d_in, const int* in_sizes, int n_in,
                              void* d_out, int out_size, void* d_ws, size_t ws_size,
                              hipStream_t stream)
{
    const float* x       = (const float*)d_in[0];
    const float* cache_k = (const float*)d_in[1];
    const float* cache_v = (const float*)d_in[2];
    const float* Wqkv    = (const float*)d_in[3];
    const float* bqkv    = (const float*)d_in[4];
    const float* Wproj   = (const float*)d_in[5];
    const float* bproj   = (const float*)d_in[6];
    // d_in[7] = cache_pos (always P per setup; unused by the math)

    float* qkv      = (float*)d_ws;           // B*HQKV floats
    float* attn_out = qkv + B * HQKV;         // B*H floats
    float* out      = (float*)d_out;

    void* args[] = { (void*)&x, (void*)&cache_k, (void*)&cache_v,
                     (void*)&Wqkv, (void*)&bqkv, (void*)&Wproj, (void*)&bproj,
                     (void*)&qkv, (void*)&attn_out, (void*)&out };

    hipLaunchCooperativeKernel((void*)fused_attn_kernel,
                               dim3(B * NH), dim3(1024), args, 0, stream);
}

// Round 3
// 738.957 us; speedup vs baseline: 1.1008x; 1.1008x over previous
//
#include <hip/hip_runtime.h>

#define B 8
#define H 4096
#define NH 32
#define HD 128
#define P 2047
#define T 2048          // P + 1 (cache + appended token)
#define HQKV 12288      // 3*H

#define TS 8            // attention t-splits
#define TC 256          // T / TS tokens per split
#define AW 4            // waves per attn block

// ---------------------------------------------------------------------------
// Kernel 0: seed qkv ws with bqkv and d_out with bproj (atomic k-split targets).
// ---------------------------------------------------------------------------
__global__ __launch_bounds__(256) void init_bias_kernel(
    const float* __restrict__ bqkv, const float* __restrict__ bproj,
    float* __restrict__ qkv, float* __restrict__ out)
{
    int i = blockIdx.x * 256 + threadIdx.x;      // [0, 32768) float4s
    if (i < 24576) {                             // qkv: 24576 float4
        ((float4*)qkv)[i] = ((const float4*)bqkv)[i % (HQKV / 4)];
    } else {
        int j = i - 24576;                       // out: 8192 float4
        ((float4*)out)[j] = ((const float4*)bproj)[j & (H / 4 - 1)];
    }
}

// ---------------------------------------------------------------------------
// Kernel 1: qkv += x @ Wqkv. 12 col-blocks (1024 cols) x 32 k-chunks = 384
// blocks x 256 thr. k-step 8 -> 8 independent 1KB wave-loads in flight.
// ---------------------------------------------------------------------------
__global__ __launch_bounds__(256) void qkv_gemm_kernel(
    const float* __restrict__ x, const float* __restrict__ W,
    float* __restrict__ qkv)
{
    const int cb = blockIdx.x % 12;
    const int kc = blockIdx.x / 12;
    const int c0 = cb * 1024 + threadIdx.x * 4;
    const int k0 = kc * 128;

    float4 acc[B];
#pragma unroll
    for (int b = 0; b < B; ++b) acc[b] = make_float4(0.f, 0.f, 0.f, 0.f);

    const float* wp = W + (size_t)k0 * HQKV + c0;
    const float* xp = x + k0;

    for (int k = 0; k < 128; k += 8) {
        float4 wr[8];
#pragma unroll
        for (int r = 0; r < 8; ++r)
            wr[r] = *(const float4*)(wp + (size_t)(k + r) * HQKV);
#pragma unroll
        for (int b = 0; b < B; ++b) {
            float4 x0 = *(const float4*)(xp + b * H + k);      // wave-uniform
            float4 x1 = *(const float4*)(xp + b * H + k + 4);
            acc[b].x += x0.x*wr[0].x + x0.y*wr[1].x + x0.z*wr[2].x + x0.w*wr[3].x
                      + x1.x*wr[4].x + x1.y*wr[5].x + x1.z*wr[6].x + x1.w*wr[7].x;
            acc[b].y += x0.x*wr[0].y + x0.y*wr[1].y + x0.z*wr[2].y + x0.w*wr[3].y
                      + x1.x*wr[4].y + x1.y*wr[5].y + x1.z*wr[6].y + x1.w*wr[7].y;
            acc[b].z += x0.x*wr[0].z + x0.y*wr[1].z + x0.z*wr[2].z + x0.w*wr[3].z
                      + x1.x*wr[4].z + x1.y*wr[5].z + x1.z*wr[6].z + x1.w*wr[7].z;
            acc[b].w += x0.x*wr[0].w + x0.y*wr[1].w + x0.z*wr[2].w + x0.w*wr[3].w
                      + x1.x*wr[4].w + x1.y*wr[5].w + x1.z*wr[6].w + x1.w*wr[7].w;
        }
    }
#pragma unroll
    for (int b = 0; b < B; ++b) {
        float* q = qkv + b * HQKV + c0;
        atomicAdd(q + 0, acc[b].x);
        atomicAdd(q + 1, acc[b].y);
        atomicAdd(q + 2, acc[b].z);
        atomicAdd(q + 3, acc[b].w);
    }
}

// ---------------------------------------------------------------------------
// Kernel 2: flash-decode partials. Block = (b,h,ts), 256 thr (4 waves).
// Batch-8 float4 loads (4KB in flight/wave) before any reduce chain.
// Emits unnormalized partial O plus (m, l) per split.
// ---------------------------------------------------------------------------
__global__ __launch_bounds__(256) void attn_partial_kernel(
    const float* __restrict__ cache_k, const float* __restrict__ cache_v,
    const float* __restrict__ qkv,
    float* __restrict__ part_O, float* __restrict__ part_ml)
{
    __shared__ float sc[TC];
    __shared__ float red[AW];
    __shared__ float ored[AW][HD];
    __shared__ float stats[2];

    const int bh = blockIdx.x / TS;          // [0,256)
    const int ts = blockIdx.x % TS;
    const int b  = bh >> 5;
    const int h  = bh & 31;
    const int tid  = threadIdx.x;
    const int w    = tid >> 6;
    const int lane = tid & 63;
    const int sl   = lane & 31;              // sub-lane in half-wave
    const int half = lane >> 5;              // half-wave -> t parity
    const size_t tstride = (size_t)B * NH * HD;
    const float scale = 0.08838834764831845f;   // 1/sqrt(128)
    const int t0 = ts * TC;

    float4 q4 = *(const float4*)(qkv + b * HQKV + h * HD + 4 * sl);
    const float* kb = cache_k + ((size_t)b * NH + h) * HD + 4 * sl;
    const float* kn = qkv + b * HQKV + H + h * HD + 4 * sl;

    // ---- phase 1: scores (8 loads batched per wave-iter) ----
    for (int i = 0; i < TC / 64; ++i) {      // 4 iters; 32 pairs/block-iter
        const int lp0 = i * 32 + w * 8;
        float4 kk[8];
#pragma unroll
        for (int j = 0; j < 8; ++j) {
            int t = t0 + 2 * (lp0 + j) + half;
            const float* kp = (t < P) ? (kb + (size_t)t * tstride) : kn;
            kk[j] = *(const float4*)kp;
        }
#pragma unroll
        for (int j = 0; j < 8; ++j) {
            float ps = q4.x*kk[j].x + q4.y*kk[j].y + q4.z*kk[j].z + q4.w*kk[j].w;
#pragma unroll
            for (int off = 16; off >= 1; off >>= 1) ps += __shfl_xor(ps, off);
            if (sl == 0) sc[2 * (lp0 + j) + half] = ps * scale;
        }
    }
    __syncthreads();

    // ---- local softmax stats over TC entries (1/thread) ----
    float m = sc[tid];
#pragma unroll
    for (int off = 32; off >= 1; off >>= 1) m = fmaxf(m, __shfl_xor(m, off));
    if (lane == 0) red[w] = m;
    __syncthreads();
    if (tid == 0)
        stats[0] = fmaxf(fmaxf(red[0], red[1]), fmaxf(red[2], red[3]));
    __syncthreads();
    const float lm = stats[0];
    float p = __expf(sc[tid] - lm);
    sc[tid] = p;
    float ls = p;
#pragma unroll
    for (int off = 32; off >= 1; off >>= 1) ls += __shfl_xor(ls, off);
    if (lane == 0) red[w] = ls;
    __syncthreads();
    if (tid == 0) stats[1] = red[0] + red[1] + red[2] + red[3];

    // ---- phase 2: unnormalized O partial ----
    const float* vb = cache_v + ((size_t)b * NH + h) * HD + 4 * sl;
    const float* vn = qkv + b * HQKV + 2 * H + h * HD + 4 * sl;
    float4 o4 = make_float4(0.f, 0.f, 0.f, 0.f);
    for (int i = 0; i < TC / 64; ++i) {
        const int lp0 = i * 32 + w * 8;
        float4 vv[8];
#pragma unroll
        for (int j = 0; j < 8; ++j) {
            int t = t0 + 2 * (lp0 + j) + half;
            const float* vp = (t < P) ? (vb + (size_t)t * tstride) : vn;
            vv[j] = *(const float4*)vp;
        }
#pragma unroll
        for (int j = 0; j < 8; ++j) {
            float pw = sc[2 * (lp0 + j) + half];
            o4.x += pw * vv[j].x; o4.y += pw * vv[j].y;
            o4.z += pw * vv[j].z; o4.w += pw * vv[j].w;
        }
    }
    o4.x += __shfl_xor(o4.x, 32);
    o4.y += __shfl_xor(o4.y, 32);
    o4.z += __shfl_xor(o4.z, 32);
    o4.w += __shfl_xor(o4.w, 32);
    if (half == 0) *(float4*)&ored[w][4 * sl] = o4;
    __syncthreads();
    if (tid < HD) {
        float s = ored[0][tid] + ored[1][tid] + ored[2][tid] + ored[3][tid];
        part_O[((size_t)bh * TS + ts) * HD + tid] = s;
    }
    if (tid == 0) {
        part_ml[(bh * TS + ts) * 2 + 0] = stats[0];
        part_ml[(bh * TS + ts) * 2 + 1] = stats[1];
    }
}

// ---------------------------------------------------------------------------
// Kernel 3: combine partials -> attn_out. 256 blocks x 128 thr.
// ---------------------------------------------------------------------------
__global__ __launch_bounds__(128) void attn_combine_kernel(
    const float* __restrict__ part_O, const float* __restrict__ part_ml,
    float* __restrict__ attn_out)
{
    const int bh = blockIdx.x;
    const int d  = threadIdx.x;

    float mvals[TS], lvals[TS];
    float gm = -1e30f;
#pragma unroll
    for (int s = 0; s < TS; ++s) {
        mvals[s] = part_ml[(bh * TS + s) * 2 + 0];
        lvals[s] = part_ml[(bh * TS + s) * 2 + 1];
        gm = fmaxf(gm, mvals[s]);
    }
    float gl = 0.f, o = 0.f;
#pragma unroll
    for (int s = 0; s < TS; ++s) {
        float f = __expf(mvals[s] - gm);
        gl += f * lvals[s];
        o  += f * part_O[((size_t)bh * TS + s) * HD + d];
    }
    attn_out[bh * HD + d] = o / gl;
}

// ---------------------------------------------------------------------------
// Kernel 4: out += attn_out @ Wproj. 4 col-blocks x 64 k-chunks = 256 blocks.
// ---------------------------------------------------------------------------
__global__ __launch_bounds__(256) void proj_gemm_kernel(
    const float* __restrict__ attn, const float* __restrict__ W,
    float* __restrict__ out)
{
    const int cb = blockIdx.x % 4;
    const int kc = blockIdx.x / 4;
    const int c0 = cb * 1024 + threadIdx.x * 4;
    const int k0 = kc * 64;

    float4 acc[B];
#pragma unroll
    for (int b = 0; b < B; ++b) acc[b] = make_float4(0.f, 0.f, 0.f, 0.f);

    const float* wp = W + (size_t)k0 * H + c0;
    const float* xp = attn + k0;

    for (int k = 0; k < 64; k += 8) {
        float4 wr[8];
#pragma unroll
        for (int r = 0; r < 8; ++r)
            wr[r] = *(const float4*)(wp + (size_t)(k + r) * H);
#pragma unroll
        for (int b = 0; b < B; ++b) {
            float4 x0 = *(const float4*)(xp + b * H + k);      // wave-uniform
            float4 x1 = *(const float4*)(xp + b * H + k + 4);
            acc[b].x += x0.x*wr[0].x + x0.y*wr[1].x + x0.z*wr[2].x + x0.w*wr[3].x
                      + x1.x*wr[4].x + x1.y*wr[5].x + x1.z*wr[6].x + x1.w*wr[7].x;
            acc[b].y += x0.x*wr[0].y + x0.y*wr[1].y + x0.z*wr[2].y + x0.w*wr[3].y
                      + x1.x*wr[4].y + x1.y*wr[5].y + x1.z*wr[6].y + x1.w*wr[7].y;
            acc[b].z += x0.x*wr[0].z + x0.y*wr[1].z + x0.z*wr[2].z + x0.w*wr[3].z
                      + x1.x*wr[4].z + x1.y*wr[5].z + x1.z*wr[6].z + x1.w*wr[7].z;
            acc[b].w += x0.x*wr[0].w + x0.y*wr[1].w + x0.z*wr[2].w + x0.w*wr[3].w
                      + x1.x*wr[4].w + x1.y*wr[5].w + x1.z*wr[6].w + x1.w*wr[7].w;
        }
    }
#pragma unroll
    for (int b = 0; b < B; ++b) {
        float* o = out + b * H + c0;
        atomicAdd(o + 0, acc[b].x);
        atomicAdd(o + 1, acc[b].y);
        atomicAdd(o + 2, acc[b].z);
        atomicAdd(o + 3, acc[b].w);
    }
}

// ---------------------------------------------------------------------------
extern "C" void kernel_launch(void* const* d_in, const int* in_sizes, int n_in,
                              void* d_out, int out_size, void* d_ws, size_t ws_size,
                              hipStream_t stream)
{
    const float* x       = (const float*)d_in[0];
    const float* cache_k = (const float*)d_in[1];
    const float* cache_v = (const float*)d_in[2];
    const float* Wqkv    = (const float*)d_in[3];
    const float* bqkv    = (const float*)d_in[4];
    const float* Wproj   = (const float*)d_in[5];
    const float* bproj   = (const float*)d_in[6];
    // d_in[7] = cache_pos (always P; unused by the math)

    float* qkv      = (float*)d_ws;                 // B*HQKV
    float* attn_out = qkv + B * HQKV;               // B*H
    float* part_O   = attn_out + B * H;             // 256*TS*HD
    float* part_ml  = part_O + 256 * TS * HD;       // 256*TS*2
    float* out      = (float*)d_out;

    hipLaunchKernelGGL(init_bias_kernel, dim3(128), dim3(256), 0, stream,
                       bqkv, bproj, qkv, out);
    hipLaunchKernelGGL(qkv_gemm_kernel, dim3(384), dim3(256), 0, stream,
                       x, Wqkv, qkv);
    hipLaunchKernelGGL(attn_partial_kernel, dim3(256 * TS), dim3(256), 0, stream,
                       cache_k, cache_v, qkv, part_O, part_ml);
    hipLaunchKernelGGL(attn_combine_kernel, dim3(256), dim3(128), 0, stream,
                       part_O, part_ml, attn_out);
    hipLaunchKernelGGL(proj_gemm_kernel, dim3(256), dim3(256), 0, stream,
                       attn_out, Wproj, out);
}